// Round 4
// baseline (754.376 us; speedup 1.0000x reference)
//
#include <hip/hip_runtime.h>
#include <math.h>

// ---- problem constants ----
#define N_SAMP 441000
#define BATCH  16
#define N_Q    110250          // quads per row
#define KQ_PAD 110592          // 432 chunks * 256 quads
#define C_Q    256             // chunk length in quads (1024 samples)
#define W_Q    8192            // warmup quads (32768 samples)
#define NCHUNK 432
#define NWAVE  108             // 432 chunks / 4 per wave
#define PSTR4  442368          // float4 per K plane (KQ_PAD/4 * 16)
#define PLANE_F (4 * PSTR4)    // floats per K plane

#define A_AT  0.9977349953069123f
#define A_REL 0.9997732683378945f
#define OMA_AT  (1.0f - A_AT)
#define OMA_REL (1.0f - A_REL)

// s_waitcnt imm: vmcnt<=50, expcnt/lgkmcnt unconstrained
// imm = (50&15) | (7<<4) | (15<<8) | ((50>>4)<<14) = 2+112+3840+49152
#define WAITCNT_VM50 53106

#define GLD16(gp, lp) __builtin_amdgcn_global_load_lds( \
    (const __attribute__((address_space(1))) unsigned int*)(gp), \
    (__attribute__((address_space(3))) unsigned int*)(lp), 16, 0, 0)

static __device__ __forceinline__ float rect_db_f(float xv) {
    return 6.020599913279624f * log2f(fabsf(xv) + 1e-8f);
}
static __device__ __forceinline__ float step_v(float s, float v) {
    return fmaxf(fmaf(A_AT, s, OMA_AT * v), fmaf(A_REL, s, OMA_REL * v));
}
static __device__ __forceinline__ float gain_mul(float s, float th, float dp) {
    float ddn = s - th;
    float gdn = 0.0f;
    if (ddn > -0.1f) {
        float dm = ddn - 0.1f;
        gdn = -0.4925037481259370f * (ddn + 0.1f + sqrtf(fmaf(dm, dm, 1e-4f)));
    }
    float dup = th - s;
    float gup = 0.0f;
    if (dup > -0.1f) {
        float um = dup - 0.1f;
        gup = 0.45f * (dup + 0.1f + sqrtf(fmaf(um, um, 1e-4f)));
    }
    gup = fminf(gup, 36.0f);
    return exp2f((gdn + gup) * dp * 0.1660964047443681f);
}

// ---- Pass 0: per-quad composite coefficients; thread id == K linear addr ----
// K[c][gq][b][slot]; thread l = gq*64 + b*4 + slot -> stores at c*PLANE_F + l
__global__ __launch_bounds__(256) void coef_kernel(const float* __restrict__ x,
                                                   float* __restrict__ K) {
    int l = blockIdx.x * 256 + threadIdx.x;
    int slot = l & 3, b = (l >> 2) & 15, gq = l >> 6;
    int t = gq * 4 + slot;
    if (t >= N_Q) return;
    float4 xq = ((const float4*)x)[b * N_Q + t];
    float v0 = rect_db_f(xq.x), v1 = rect_db_f(xq.y);
    float v2 = rect_db_f(xq.z), v3 = rect_db_f(xq.w);
    float p0 = OMA_AT * v0, q0 = OMA_REL * v0;
    float p1 = OMA_AT * v1, q1 = OMA_REL * v1;
    float p2 = OMA_AT * v2, q2 = OMA_REL * v2;
    float p3 = OMA_AT * v3, q3 = OMA_REL * v3;
    float o1_1 = p0, o1_0 = q0;
    float o2_2 = fmaf(A_AT, o1_1, p1);
    float o2_1 = fmaxf(fmaf(A_AT, o1_0, p1), fmaf(A_REL, o1_1, q1));
    float o2_0 = fmaf(A_REL, o1_0, q1);
    float o3_3 = fmaf(A_AT, o2_2, p2);
    float o3_2 = fmaxf(fmaf(A_AT, o2_1, p2), fmaf(A_REL, o2_2, q2));
    float o3_1 = fmaxf(fmaf(A_AT, o2_0, p2), fmaf(A_REL, o2_1, q2));
    float o3_0 = fmaf(A_REL, o2_0, q2);
    float K4 = fmaf(A_AT, o3_3, p3);
    float K3 = fmaxf(fmaf(A_AT, o3_2, p3), fmaf(A_REL, o3_3, q3));
    float K2 = fmaxf(fmaf(A_AT, o3_1, p3), fmaf(A_REL, o3_2, q3));
    float K1 = fmaxf(fmaf(A_AT, o3_0, p3), fmaf(A_REL, o3_1, q3));
    float K0 = fmaf(A_REL, o3_0, q3);
    K[l]               = K0;
    K[PLANE_F + l]     = K1;
    K[2 * PLANE_F + l] = K2;
    K[3 * PLANE_F + l] = K3;
    K[4 * PLANE_F + l] = K4;
}

// ---- Pass 1: serial scan; LDS ring + global_load_lds, fine-grained vmcnt ----
__global__ __launch_bounds__(64) void scan_kernel(const float* __restrict__ Kf,
                                                  const float* __restrict__ x,
                                                  float* __restrict__ level_q) {
    const int w    = blockIdx.x;            // 0..107
    const int lane = threadIdx.x;
    const int grp  = lane >> 4;             // 0..3
    const int b    = lane & 15;
    const int k    = 4 * w + grp;           // chunk id
    const int g0   = max(0, (k - 32) * C_Q);
    const int nblk = (w >= 8) ? ((W_Q + C_Q) / 8) : ((4 * w + 4) * (C_Q / 8));
    const int emit0 = (w >= 8) ? (W_Q / 8) : (k * (C_Q / 8));

    const float S0 = A_REL * A_REL * A_REL * A_REL;
    const float S1 = A_AT * A_REL * A_REL * A_REL;
    const float S2 = A_AT * A_AT * A_REL * A_REL;
    const float S3 = A_AT * A_AT * A_AT * A_REL;
    const float S4 = A_AT * A_AT * A_AT * A_AT;

    // ring: 6 slots x (5 planes x 2 halves) x 64 lanes x float4 = 60 KB
    __shared__ float4 ring[6][10][64];

    const float4* gb = (const float4*)Kf + (size_t)(g0 >> 2) * 16 + b;

    // seed (consume immediately so its waitcnt lands before the prologue)
    float s = rect_db_f(x[(size_t)b * N_SAMP + 4 * g0]);

    // prologue: prefetch blocks 0..4 into slots 0..4
    #pragma unroll
    for (int pf = 0; pf < 5; ++pf) {
        const float4* gp = gb + pf * 32;
        #pragma unroll
        for (int p = 0; p < 5; ++p) {
            GLD16(gp + p * PSTR4,      &ring[pf][2 * p][0]);
            GLD16(gp + p * PSTR4 + 16, &ring[pf][2 * p + 1][0]);
        }
    }

    float* lp = level_q + (size_t)b * KQ_PAD + g0;

    int rs = 0;  // read slot for block i; prefetch slot = (rs+5)%6 = (rs-1)%6
    for (int i = 0; i < nblk; ++i) {
        // prefetch block i+5 into the slot consumed at i-1
        const int ws = (rs == 0) ? 5 : (rs - 1);
        const float4* gp = gb + (i + 5) * 32;
        #pragma unroll
        for (int p = 0; p < 5; ++p) {
            GLD16(gp + p * PSTR4,      &ring[ws][2 * p][0]);
            GLD16(gp + p * PSTR4 + 16, &ring[ws][2 * p + 1][0]);
        }
        // wait for block i's 10 loads (50 newer loads stay in flight), no drain
        __builtin_amdgcn_s_waitcnt(WAITCNT_VM50);
        __builtin_amdgcn_s_barrier();

        const float4* sl = &ring[rs][0][lane];
        const bool em = (i >= emit0);
        #pragma unroll
        for (int h = 0; h < 2; ++h) {
            float4 a0 = sl[(0 * 2 + h) * 64];
            float4 a1 = sl[(1 * 2 + h) * 64];
            float4 a2 = sl[(2 * 2 + h) * 64];
            float4 a3 = sl[(3 * 2 + h) * 64];
            float4 a4 = sl[(4 * 2 + h) * 64];
            float4 r;
            float c0, c1, c2, c3, c4;
            c0 = fmaf(S0, s, a0.x); c1 = fmaf(S1, s, a1.x); c2 = fmaf(S2, s, a2.x);
            c3 = fmaf(S3, s, a3.x); c4 = fmaf(S4, s, a4.x);
            s = fmaxf(fmaxf(fmaxf(c0, c1), fmaxf(c2, c3)), c4); r.x = s;
            c0 = fmaf(S0, s, a0.y); c1 = fmaf(S1, s, a1.y); c2 = fmaf(S2, s, a2.y);
            c3 = fmaf(S3, s, a3.y); c4 = fmaf(S4, s, a4.y);
            s = fmaxf(fmaxf(fmaxf(c0, c1), fmaxf(c2, c3)), c4); r.y = s;
            c0 = fmaf(S0, s, a0.z); c1 = fmaf(S1, s, a1.z); c2 = fmaf(S2, s, a2.z);
            c3 = fmaf(S3, s, a3.z); c4 = fmaf(S4, s, a4.z);
            s = fmaxf(fmaxf(fmaxf(c0, c1), fmaxf(c2, c3)), c4); r.z = s;
            c0 = fmaf(S0, s, a0.w); c1 = fmaf(S1, s, a1.w); c2 = fmaf(S2, s, a2.w);
            c3 = fmaf(S3, s, a3.w); c4 = fmaf(S4, s, a4.w);
            s = fmaxf(fmaxf(fmaxf(c0, c1), fmaxf(c2, c3)), c4); r.w = s;
            if (em) *(float4*)(lp + (size_t)i * 8 + h * 4) = r;
        }
        rs = (rs == 5) ? 0 : (rs + 1);
    }
}

// ---- Pass 2: intra-quad reconstruction + gain + output (parallel) ----
__global__ __launch_bounds__(256) void out_kernel(const float* __restrict__ x,
                                                  const float* __restrict__ level_q,
                                                  const float* __restrict__ thr,
                                                  const float* __restrict__ dep,
                                                  float* __restrict__ out) {
    int t = blockIdx.x * 256 + threadIdx.x;
    int b = blockIdx.y;
    if (t >= N_Q) return;
    float4 xq = ((const float4*)x)[b * N_Q + t];
    float v0 = rect_db_f(xq.x), v1 = rect_db_f(xq.y);
    float v2 = rect_db_f(xq.z), v3 = rect_db_f(xq.w);
    float s = (t == 0) ? v0 : level_q[(size_t)b * KQ_PAD + t - 1];
    float l0 = step_v(s, v0);
    float l1 = step_v(l0, v1);
    float l2 = step_v(l1, v2);
    float l3 = step_v(l2, v3);
    float th = fmaf(thr[b], 40.0f, -40.0f);
    float dp = dep[b];
    float4 o;
    o.x = xq.x * gain_mul(l0, th, dp);
    o.y = xq.y * gain_mul(l1, th, dp);
    o.z = xq.z * gain_mul(l2, th, dp);
    o.w = xq.w * gain_mul(l3, th, dp);
    ((float4*)out)[b * N_Q + t] = o;
}

// ---- Fallback (tiny ws): slow but correct fused scan ----
__global__ __launch_bounds__(64) void scan_fused(const float* __restrict__ x,
                                                 const float* __restrict__ thr,
                                                 const float* __restrict__ dep,
                                                 float* __restrict__ out) {
    int t = blockIdx.x * 64 + threadIdx.x;
    const int NCH = 54, CH = 8192, WM = 32768;
    if (t >= BATCH * NCH) return;
    int b = t / NCH, k = t - b * NCH;
    int start = k * CH, end = min(start + CH, N_SAMP), w0 = max(start - WM, 0);
    const float* xr = x + (size_t)b * N_SAMP;
    float th = fmaf(thr[b], 40.0f, -40.0f);
    float dp = dep[b];
    float s = rect_db_f(xr[w0]);
    for (int j = w0; j < start; ++j) s = step_v(s, rect_db_f(xr[j]));
    float* orow = out + (size_t)b * N_SAMP;
    for (int j = start; j < end; ++j) {
        float xv = xr[j];
        s = step_v(s, rect_db_f(xv));
        orow[j] = xv * gain_mul(s, th, dp);
    }
}

extern "C" void kernel_launch(void* const* d_in, const int* in_sizes, int n_in,
                              void* d_out, int out_size, void* d_ws, size_t ws_size,
                              hipStream_t stream) {
    const float* x   = (const float*)d_in[0];
    const float* thr = (const float*)d_in[1];
    const float* dep = (const float*)d_in[2];
    float* out = (float*)d_out;

    const size_t k_bytes  = (size_t)5 * PLANE_F * sizeof(float);   // 35.4 MB
    const size_t lq_bytes = (size_t)BATCH * KQ_PAD * sizeof(float); // 7.08 MB

    if (ws_size >= k_bytes + lq_bytes) {
        float* K       = (float*)d_ws;
        float* level_q = (float*)((char*)d_ws + k_bytes);
        const int nthread = ((N_Q + 3) / 4) * 64;                  // 1,764,032
        coef_kernel<<<(nthread + 255) / 256, 256, 0, stream>>>(x, K);
        scan_kernel<<<NWAVE, 64, 0, stream>>>(K, x, level_q);
        dim3 gpar((N_Q + 255) / 256, BATCH);
        out_kernel<<<gpar, 256, 0, stream>>>(x, level_q, thr, dep, out);
    } else {
        scan_fused<<<(BATCH * 54 + 63) / 64, 64, 0, stream>>>(x, thr, dep, out);
    }
}

// Round 6
// 363.224 us; speedup vs baseline: 2.0769x; 2.0769x over previous
//
#include <hip/hip_runtime.h>
#include <math.h>

// ---- problem constants ----
#define N_SAMP 441000
#define BATCH  16
#define N_Q    110250          // quads per row
#define KQ_PAD 110592          // 108 chunks * 1024 quads
#define C_Q    1024            // chunk length in quads (4096 samples)
#define W_Q    8192            // warmup quads (32768 samples) -- release-rate bound, do not shrink
#define NCHUNK 108
#define NWAVE  27              // 108 chunks / 4 per wave
#define PSTR4  442368          // float4 per K plane (KQ_PAD/4 * 16)
#define PLANE_F (4 * PSTR4)    // floats per K plane

#define A_AT  0.9977349953069123f
#define A_REL 0.9997732683378945f
#define OMA_AT  (1.0f - A_AT)
#define OMA_REL (1.0f - A_REL)

static __device__ __forceinline__ float rect_db_f(float xv) {
    return 6.020599913279624f * log2f(fabsf(xv) + 1e-8f);
}
static __device__ __forceinline__ float step_v(float s, float v) {
    return fmaxf(fmaf(A_AT, s, OMA_AT * v), fmaf(A_REL, s, OMA_REL * v));
}
static __device__ __forceinline__ float gain_mul(float s, float th, float dp) {
    float ddn = s - th;
    float gdn = 0.0f;
    if (ddn > -0.1f) {
        float dm = ddn - 0.1f;
        gdn = -0.4925037481259370f * (ddn + 0.1f + sqrtf(fmaf(dm, dm, 1e-4f)));
    }
    float dup = th - s;
    float gup = 0.0f;
    if (dup > -0.1f) {
        float um = dup - 0.1f;
        gup = 0.45f * (dup + 0.1f + sqrtf(fmaf(um, um, 1e-4f)));
    }
    gup = fminf(gup, 36.0f);
    return exp2f((gdn + gup) * dp * 0.1660964047443681f);
}

// ---- Pass 0: per-quad composite coefficients; thread id == K linear addr ----
// K[c][gq][b][slot]; thread l = gq*64 + b*4 + slot -> stores at c*PLANE_F + l
__global__ __launch_bounds__(256) void coef_kernel(const float* __restrict__ x,
                                                   float* __restrict__ K) {
    int l = blockIdx.x * 256 + threadIdx.x;
    int slot = l & 3, b = (l >> 2) & 15, gq = l >> 6;
    int t = gq * 4 + slot;
    if (t >= N_Q) return;
    float4 xq = ((const float4*)x)[b * N_Q + t];
    float v0 = rect_db_f(xq.x), v1 = rect_db_f(xq.y);
    float v2 = rect_db_f(xq.z), v3 = rect_db_f(xq.w);
    float p0 = OMA_AT * v0, q0 = OMA_REL * v0;
    float p1 = OMA_AT * v1, q1 = OMA_REL * v1;
    float p2 = OMA_AT * v2, q2 = OMA_REL * v2;
    float p3 = OMA_AT * v3, q3 = OMA_REL * v3;
    float o1_1 = p0, o1_0 = q0;
    float o2_2 = fmaf(A_AT, o1_1, p1);
    float o2_1 = fmaxf(fmaf(A_AT, o1_0, p1), fmaf(A_REL, o1_1, q1));
    float o2_0 = fmaf(A_REL, o1_0, q1);
    float o3_3 = fmaf(A_AT, o2_2, p2);
    float o3_2 = fmaxf(fmaf(A_AT, o2_1, p2), fmaf(A_REL, o2_2, q2));
    float o3_1 = fmaxf(fmaf(A_AT, o2_0, p2), fmaf(A_REL, o2_1, q2));
    float o3_0 = fmaf(A_REL, o2_0, q2);
    float K4 = fmaf(A_AT, o3_3, p3);
    float K3 = fmaxf(fmaf(A_AT, o3_2, p3), fmaf(A_REL, o3_3, q3));
    float K2 = fmaxf(fmaf(A_AT, o3_1, p3), fmaf(A_REL, o3_2, q3));
    float K1 = fmaxf(fmaf(A_AT, o3_0, p3), fmaf(A_REL, o3_1, q3));
    float K0 = fmaf(A_REL, o3_0, q3);
    K[l]               = K0;
    K[PLANE_F + l]     = K1;
    K[2 * PLANE_F + l] = K2;
    K[3 * PLANE_F + l] = K3;
    K[4 * PLANE_F + l] = K4;
}

// ---- Pass 1: serial scan; named-register ring, distance-3 prefetch ----
// Ring slot = 10 named float4 (5 planes x 2 halves of an 8-quad block).
// NOTE: `n##2 .x` (space!) -- `2.x` would lex as one pp-number token.
#define SLOT_DECL(n) float4 n##0, n##1, n##2, n##3, n##4, n##5, n##6, n##7, n##8, n##9

#define LOAD_SLOT(n, blk) do {                                           \
    int _o = (blk) * 32;                                                 \
    n##0 = gp[_o];                 n##1 = gp[_o + 16];                   \
    n##2 = gp[PSTR4 + _o];         n##3 = gp[PSTR4 + _o + 16];           \
    n##4 = gp[2 * PSTR4 + _o];     n##5 = gp[2 * PSTR4 + _o + 16];       \
    n##6 = gp[3 * PSTR4 + _o];     n##7 = gp[3 * PSTR4 + _o + 16];       \
    n##8 = gp[4 * PSTR4 + _o];     n##9 = gp[4 * PSTR4 + _o + 16];       \
} while (0)

#define STEP1(k0v, k1v, k2v, k3v, k4v, dst) do {                         \
    float c0 = fmaf(S0, s, k0v), c1 = fmaf(S1, s, k1v);                  \
    float c2 = fmaf(S2, s, k2v), c3 = fmaf(S3, s, k3v);                  \
    float c4 = fmaf(S4, s, k4v);                                         \
    s = fmaxf(fmaxf(fmaxf(c0, c1), fmaxf(c2, c3)), c4);                  \
    dst = s;                                                             \
} while (0)

#define COMPUTE_SLOT(n, i) do {                                          \
    float4 o1, o2;                                                       \
    STEP1(n##0 .x, n##2 .x, n##4 .x, n##6 .x, n##8 .x, o1.x);            \
    STEP1(n##0 .y, n##2 .y, n##4 .y, n##6 .y, n##8 .y, o1.y);            \
    STEP1(n##0 .z, n##2 .z, n##4 .z, n##6 .z, n##8 .z, o1.z);            \
    STEP1(n##0 .w, n##2 .w, n##4 .w, n##6 .w, n##8 .w, o1.w);            \
    STEP1(n##1 .x, n##3 .x, n##5 .x, n##7 .x, n##9 .x, o2.x);            \
    STEP1(n##1 .y, n##3 .y, n##5 .y, n##7 .y, n##9 .y, o2.y);            \
    STEP1(n##1 .z, n##3 .z, n##5 .z, n##7 .z, n##9 .z, o2.z);            \
    STEP1(n##1 .w, n##3 .w, n##5 .w, n##7 .w, n##9 .w, o2.w);            \
    if ((i) >= emit0 && (i) < emit1) {                                   \
        *(float4*)(lp + (size_t)(i) * 8)     = o1;                       \
        *(float4*)(lp + (size_t)(i) * 8 + 4) = o2;                       \
    }                                                                    \
} while (0)

__global__ __launch_bounds__(64, 1) void scan_kernel(const float* __restrict__ Kf,
                                                     const float* __restrict__ x,
                                                     float* __restrict__ level_q) {
    const int w    = blockIdx.x;            // 0..26
    const int lane = threadIdx.x;
    const int grp  = lane >> 4;             // 0..3
    const int b    = lane & 15;
    const int k    = 4 * w + grp;           // chunk id 0..107
    const int g0   = max(0, (k - 8) * C_Q);
    const int nblk = (w >= 2) ? ((W_Q + C_Q) / 8) : ((4 * w + 4) * (C_Q / 8)); // wave-uniform
    const int emit0 = (w >= 2) ? (W_Q / 8) : (k * (C_Q / 8));  // per-lane
    const int emit1 = emit0 + (C_Q / 8);
    const int nb1  = nblk - 1;

    const float S0 = A_REL * A_REL * A_REL * A_REL;
    const float S1 = A_AT * A_REL * A_REL * A_REL;
    const float S2 = A_AT * A_AT * A_REL * A_REL;
    const float S3 = A_AT * A_AT * A_AT * A_REL;
    const float S4 = A_AT * A_AT * A_AT * A_AT;

    const float4* gp = (const float4*)Kf + (size_t)(g0 >> 2) * 16 + b;
    float* lp = level_q + (size_t)b * KQ_PAD + g0;

    float s = rect_db_f(x[(size_t)b * N_SAMP + 4 * g0]);

    SLOT_DECL(r0_); SLOT_DECL(r1_); SLOT_DECL(r2_); SLOT_DECL(r3_);
    LOAD_SLOT(r0_, 0);
    LOAD_SLOT(r1_, 1);
    LOAD_SLOT(r2_, 2);

    int i = 0;
    const int nit = nblk / 4;               // nblk in {512,1024,1152}: %4==0
    for (int it = 0; it < nit; ++it) {
        LOAD_SLOT(r3_, min(i + 3, nb1)); COMPUTE_SLOT(r0_, i); ++i;
        LOAD_SLOT(r0_, min(i + 3, nb1)); COMPUTE_SLOT(r1_, i); ++i;
        LOAD_SLOT(r1_, min(i + 3, nb1)); COMPUTE_SLOT(r2_, i); ++i;
        LOAD_SLOT(r2_, min(i + 3, nb1)); COMPUTE_SLOT(r3_, i); ++i;
    }
}

// ---- Pass 2: intra-quad reconstruction + gain + output (parallel) ----
__global__ __launch_bounds__(256) void out_kernel(const float* __restrict__ x,
                                                  const float* __restrict__ level_q,
                                                  const float* __restrict__ thr,
                                                  const float* __restrict__ dep,
                                                  float* __restrict__ out) {
    int t = blockIdx.x * 256 + threadIdx.x;
    int b = blockIdx.y;
    if (t >= N_Q) return;
    float4 xq = ((const float4*)x)[b * N_Q + t];
    float v0 = rect_db_f(xq.x), v1 = rect_db_f(xq.y);
    float v2 = rect_db_f(xq.z), v3 = rect_db_f(xq.w);
    float s = (t == 0) ? v0 : level_q[(size_t)b * KQ_PAD + t - 1];
    float l0 = step_v(s, v0);
    float l1 = step_v(l0, v1);
    float l2 = step_v(l1, v2);
    float l3 = step_v(l2, v3);
    float th = fmaf(thr[b], 40.0f, -40.0f);
    float dp = dep[b];
    float4 o;
    o.x = xq.x * gain_mul(l0, th, dp);
    o.y = xq.y * gain_mul(l1, th, dp);
    o.z = xq.z * gain_mul(l2, th, dp);
    o.w = xq.w * gain_mul(l3, th, dp);
    ((float4*)out)[b * N_Q + t] = o;
}

// ---- Fallback (tiny ws): slow but correct fused scan ----
__global__ __launch_bounds__(64) void scan_fused(const float* __restrict__ x,
                                                 const float* __restrict__ thr,
                                                 const float* __restrict__ dep,
                                                 float* __restrict__ out) {
    int t = blockIdx.x * 64 + threadIdx.x;
    const int NCH = 54, CH = 8192, WM = 32768;
    if (t >= BATCH * NCH) return;
    int b = t / NCH, k = t - b * NCH;
    int start = k * CH, end = min(start + CH, N_SAMP), w0 = max(start - WM, 0);
    const float* xr = x + (size_t)b * N_SAMP;
    float th = fmaf(thr[b], 40.0f, -40.0f);
    float dp = dep[b];
    float s = rect_db_f(xr[w0]);
    for (int j = w0; j < start; ++j) s = step_v(s, rect_db_f(xr[j]));
    float* orow = out + (size_t)b * N_SAMP;
    for (int j = start; j < end; ++j) {
        float xv = xr[j];
        s = step_v(s, rect_db_f(xv));
        orow[j] = xv * gain_mul(s, th, dp);
    }
}

extern "C" void kernel_launch(void* const* d_in, const int* in_sizes, int n_in,
                              void* d_out, int out_size, void* d_ws, size_t ws_size,
                              hipStream_t stream) {
    const float* x   = (const float*)d_in[0];
    const float* thr = (const float*)d_in[1];
    const float* dep = (const float*)d_in[2];
    float* out = (float*)d_out;

    const size_t k_bytes  = (size_t)5 * PLANE_F * sizeof(float);    // 35.4 MB
    const size_t lq_bytes = (size_t)BATCH * KQ_PAD * sizeof(float); // 7.08 MB

    if (ws_size >= k_bytes + lq_bytes) {
        float* K       = (float*)d_ws;
        float* level_q = (float*)((char*)d_ws + k_bytes);
        const int nthread = ((N_Q + 3) / 4) * 64;                   // coef threads
        coef_kernel<<<(nthread + 255) / 256, 256, 0, stream>>>(x, K);
        scan_kernel<<<NWAVE, 64, 0, stream>>>(K, x, level_q);
        dim3 gpar((N_Q + 255) / 256, BATCH);
        out_kernel<<<gpar, 256, 0, stream>>>(x, level_q, thr, dep, out);
    } else {
        scan_fused<<<(BATCH * 54 + 63) / 64, 64, 0, stream>>>(x, thr, dep, out);
    }
}

// Round 10
// 348.280 us; speedup vs baseline: 2.1660x; 1.0429x over previous
//
#include <hip/hip_runtime.h>
#include <math.h>

// ---- problem constants ----
#define N_SAMP 441000
#define BATCH  16
#define N_Q    110250          // quads per row
#define KQ_PAD 110592          // 108 chunks * 1024 quads
#define C_Q    1024            // chunk length in quads (4096 samples)
#define W_Q    8192            // warmup quads (32768 samples) -- release-rate bound, do not shrink
#define NWAVE  27              // 108 chunks / 4 per wave
#define PSTR4  442368          // float4 per K plane
#define PLANE_F (4 * PSTR4)    // floats per K plane

#define A_AT  0.9977349953069123f
#define A_REL 0.9997732683378945f
#define OMA_AT  (1.0f - A_AT)
#define OMA_REL (1.0f - A_REL)

typedef float vf4 __attribute__((ext_vector_type(4)));

static __device__ __forceinline__ float rect_db_f(float xv) {
    return 6.020599913279624f * log2f(fabsf(xv) + 1e-8f);
}
static __device__ __forceinline__ float step_v(float s, float v) {
    return fmaxf(fmaf(A_AT, s, OMA_AT * v), fmaf(A_REL, s, OMA_REL * v));
}
static __device__ __forceinline__ float gain_mul(float s, float th, float dp) {
    float ddn = s - th;
    float gdn = 0.0f;
    if (ddn > -0.1f) {
        float dm = ddn - 0.1f;
        gdn = -0.4925037481259370f * (ddn + 0.1f + sqrtf(fmaf(dm, dm, 1e-4f)));
    }
    float dup = th - s;
    float gup = 0.0f;
    if (dup > -0.1f) {
        float um = dup - 0.1f;
        gup = 0.45f * (dup + 0.1f + sqrtf(fmaf(um, um, 1e-4f)));
    }
    gup = fminf(gup, 36.0f);
    return exp2f((gdn + gup) * dp * 0.1660964047443681f);
}

// ---- Pass 0: per-quad composite coefficients; thread id == K linear addr ----
__global__ __launch_bounds__(256) void coef_kernel(const float* __restrict__ x,
                                                   float* __restrict__ K) {
    int l = blockIdx.x * 256 + threadIdx.x;
    int slot = l & 3, b = (l >> 2) & 15, gq = l >> 6;
    int t = gq * 4 + slot;
    if (t >= N_Q) return;
    float4 xq = ((const float4*)x)[b * N_Q + t];
    float v0 = rect_db_f(xq.x), v1 = rect_db_f(xq.y);
    float v2 = rect_db_f(xq.z), v3 = rect_db_f(xq.w);
    float p0 = OMA_AT * v0, q0 = OMA_REL * v0;
    float p1 = OMA_AT * v1, q1 = OMA_REL * v1;
    float p2 = OMA_AT * v2, q2 = OMA_REL * v2;
    float p3 = OMA_AT * v3, q3 = OMA_REL * v3;
    float o1_1 = p0, o1_0 = q0;
    float o2_2 = fmaf(A_AT, o1_1, p1);
    float o2_1 = fmaxf(fmaf(A_AT, o1_0, p1), fmaf(A_REL, o1_1, q1));
    float o2_0 = fmaf(A_REL, o1_0, q1);
    float o3_3 = fmaf(A_AT, o2_2, p2);
    float o3_2 = fmaxf(fmaf(A_AT, o2_1, p2), fmaf(A_REL, o2_2, q2));
    float o3_1 = fmaxf(fmaf(A_AT, o2_0, p2), fmaf(A_REL, o2_1, q2));
    float o3_0 = fmaf(A_REL, o2_0, q2);
    float K4 = fmaf(A_AT, o3_3, p3);
    float K3 = fmaxf(fmaf(A_AT, o3_2, p3), fmaf(A_REL, o3_3, q3));
    float K2 = fmaxf(fmaf(A_AT, o3_1, p3), fmaf(A_REL, o3_2, q3));
    float K1 = fmaxf(fmaf(A_AT, o3_0, p3), fmaf(A_REL, o3_1, q3));
    float K0 = fmaf(A_REL, o3_0, q3);
    K[l]               = K0;
    K[PLANE_F + l]     = K1;
    K[2 * PLANE_F + l] = K2;
    K[3 * PLANE_F + l] = K3;
    K[4 * PLANE_F + l] = K4;
}

// ---- Pass 1: serial scan; 32-quad big-blocks, register double-buffer ----
// Big-block = 32 quads = 8 float4-groups x 5 planes = 40 dwordx4 per lane.
// One stall per 40 loads instead of per 10 -> latency amortized 4x vs R6.

#define LOADBB(buf, hb) do {                                              \
    const float4* _p = gp + (size_t)(hb) * 128;                           \
    _Pragma("unroll")                                                     \
    for (int _c = 0; _c < 5; ++_c) {                                      \
        _Pragma("unroll")                                                 \
        for (int _u = 0; _u < 8; ++_u)                                    \
            buf[_c][_u] = *(const vf4*)(_p + (size_t)_c * PSTR4 + _u * 16);\
    }                                                                     \
} while (0)

#define COMPBB(buf, hb) do {                                              \
    const bool _em = ((unsigned)((hb) - e0) < 32u);                       \
    float* _lp = lp + (size_t)(hb) * 32;                                  \
    _Pragma("unroll")                                                     \
    for (int _u = 0; _u < 8; ++_u) {                                      \
        vf4 _o;                                                           \
        _Pragma("unroll")                                                 \
        for (int _e = 0; _e < 4; ++_e) {                                  \
            float c0 = fmaf(S0, s, buf[0][_u][_e]);                       \
            float c1 = fmaf(S1, s, buf[1][_u][_e]);                       \
            float c2 = fmaf(S2, s, buf[2][_u][_e]);                       \
            float c3 = fmaf(S3, s, buf[3][_u][_e]);                       \
            float c4 = fmaf(S4, s, buf[4][_u][_e]);                       \
            s = fmaxf(fmaxf(fmaxf(c0, c1), fmaxf(c2, c3)), c4);           \
            _o[_e] = s;                                                   \
        }                                                                 \
        if (_em) *(vf4*)(_lp + _u * 4) = _o;                              \
    }                                                                     \
} while (0)

__global__ __launch_bounds__(64, 1) void scan_kernel(const float* __restrict__ Kf,
                                                     const float* __restrict__ x,
                                                     float* __restrict__ level_q) {
    const int w    = blockIdx.x;            // 0..26
    const int lane = threadIdx.x;
    const int grp  = lane >> 4;
    const int b    = lane & 15;
    const int k    = 4 * w + grp;           // chunk id 0..107
    const int g0   = max(0, (k - 8) * C_Q);
    // big-blocks of 32 quads: (W_Q + C_Q)/32 = 288 for full waves
    const int NHB  = (w >= 2) ? 288 : ((4 * w + 4) * 32);   // wave-uniform, even
    const int e0   = (w >= 2) ? 256 : (k * 32);             // per-lane emit start
    const int nb1  = NHB - 1;

    const float S0 = A_REL * A_REL * A_REL * A_REL;
    const float S1 = A_AT * A_REL * A_REL * A_REL;
    const float S2 = A_AT * A_AT * A_REL * A_REL;
    const float S3 = A_AT * A_AT * A_AT * A_REL;
    const float S4 = A_AT * A_AT * A_AT * A_AT;

    const float4* gp = (const float4*)Kf + (size_t)(g0 >> 2) * 16 + b;
    float* lp = level_q + (size_t)b * KQ_PAD + g0;

    float s = rect_db_f(x[(size_t)b * N_SAMP + 4 * g0]);

    vf4 A[5][8], B[5][8];                   // 320 VGPRs, reg-resident (static idx)
    LOADBB(A, 0);

    #pragma clang loop unroll(disable)
    for (int hb = 0; hb < NHB; hb += 2) {
        LOADBB(B, min(hb + 1, nb1));
        COMPBB(A, hb);
        LOADBB(A, min(hb + 2, nb1));
        COMPBB(B, hb + 1);
    }
}

// ---- Pass 2: intra-quad reconstruction + gain + output (parallel) ----
__global__ __launch_bounds__(256) void out_kernel(const float* __restrict__ x,
                                                  const float* __restrict__ level_q,
                                                  const float* __restrict__ thr,
                                                  const float* __restrict__ dep,
                                                  float* __restrict__ out) {
    int t = blockIdx.x * 256 + threadIdx.x;
    int b = blockIdx.y;
    if (t >= N_Q) return;
    float4 xq = ((const float4*)x)[b * N_Q + t];
    float v0 = rect_db_f(xq.x), v1 = rect_db_f(xq.y);
    float v2 = rect_db_f(xq.z), v3 = rect_db_f(xq.w);
    float s = (t == 0) ? v0 : level_q[(size_t)b * KQ_PAD + t - 1];
    float l0 = step_v(s, v0);
    float l1 = step_v(l0, v1);
    float l2 = step_v(l1, v2);
    float l3 = step_v(l2, v3);
    float th = fmaf(thr[b], 40.0f, -40.0f);
    float dp = dep[b];
    float4 o;
    o.x = xq.x * gain_mul(l0, th, dp);
    o.y = xq.y * gain_mul(l1, th, dp);
    o.z = xq.z * gain_mul(l2, th, dp);
    o.w = xq.w * gain_mul(l3, th, dp);
    ((float4*)out)[b * N_Q + t] = o;
}

// ---- Fallback (tiny ws): slow but correct fused scan ----
__global__ __launch_bounds__(64) void scan_fused(const float* __restrict__ x,
                                                 const float* __restrict__ thr,
                                                 const float* __restrict__ dep,
                                                 float* __restrict__ out) {
    int t = blockIdx.x * 64 + threadIdx.x;
    const int NCH = 54, CH = 8192, WM = 32768;
    if (t >= BATCH * NCH) return;
    int b = t / NCH, k = t - b * NCH;
    int start = k * CH, end = min(start + CH, N_SAMP), w0 = max(start - WM, 0);
    const float* xr = x + (size_t)b * N_SAMP;
    float th = fmaf(thr[b], 40.0f, -40.0f);
    float dp = dep[b];
    float s = rect_db_f(xr[w0]);
    for (int j = w0; j < start; ++j) s = step_v(s, rect_db_f(xr[j]));
    float* orow = out + (size_t)b * N_SAMP;
    for (int j = start; j < end; ++j) {
        float xv = xr[j];
        s = step_v(s, rect_db_f(xv));
        orow[j] = xv * gain_mul(s, th, dp);
    }
}

extern "C" void kernel_launch(void* const* d_in, const int* in_sizes, int n_in,
                              void* d_out, int out_size, void* d_ws, size_t ws_size,
                              hipStream_t stream) {
    const float* x   = (const float*)d_in[0];
    const float* thr = (const float*)d_in[1];
    const float* dep = (const float*)d_in[2];
    float* out = (float*)d_out;

    const size_t k_bytes  = (size_t)5 * PLANE_F * sizeof(float);    // 35.4 MB
    const size_t lq_bytes = (size_t)BATCH * KQ_PAD * sizeof(float); // 7.08 MB

    if (ws_size >= k_bytes + lq_bytes) {
        float* K       = (float*)d_ws;
        float* level_q = (float*)((char*)d_ws + k_bytes);
        const int nthread = ((N_Q + 3) / 4) * 64;
        coef_kernel<<<(nthread + 255) / 256, 256, 0, stream>>>(x, K);
        scan_kernel<<<NWAVE, 64, 0, stream>>>(K, x, level_q);
        dim3 gpar((N_Q + 255) / 256, BATCH);
        out_kernel<<<gpar, 256, 0, stream>>>(x, level_q, thr, dep, out);
    } else {
        scan_fused<<<(BATCH * 54 + 63) / 64, 64, 0, stream>>>(x, thr, dep, out);
    }
}

// Round 11
// 346.007 us; speedup vs baseline: 2.1802x; 1.0066x over previous
//
#include <hip/hip_runtime.h>
#include <math.h>

// ---- problem constants ----
#define N_SAMP 441000
#define BATCH  16
#define N_Q    110250          // quads per row
#define KQ_PAD 110592          // 108 chunks * 1024 quads
#define C_Q    1024            // chunk length in quads (4096 samples)
#define W_Q    8192            // warmup quads (32768 samples) -- release-rate bound, do not shrink
#define NWAVE  27              // 108 chunks / 4 per wave
#define PSTR4  442368          // float4 per K plane
#define PLANE_F (4 * PSTR4)    // floats per K plane

#define A_AT  0.9977349953069123f
#define A_REL 0.9997732683378945f
#define OMA_AT  (1.0f - A_AT)
#define OMA_REL (1.0f - A_REL)

typedef float vf4 __attribute__((ext_vector_type(4)));

static __device__ __forceinline__ float rect_db_f(float xv) {
    return 6.020599913279624f * log2f(fabsf(xv) + 1e-8f);
}
static __device__ __forceinline__ float step_v(float s, float v) {
    return fmaxf(fmaf(A_AT, s, OMA_AT * v), fmaf(A_REL, s, OMA_REL * v));
}
static __device__ __forceinline__ float gain_mul(float s, float th, float dp) {
    float ddn = s - th;
    float gdn = 0.0f;
    if (ddn > -0.1f) {
        float dm = ddn - 0.1f;
        gdn = -0.4925037481259370f * (ddn + 0.1f + sqrtf(fmaf(dm, dm, 1e-4f)));
    }
    float dup = th - s;
    float gup = 0.0f;
    if (dup > -0.1f) {
        float um = dup - 0.1f;
        gup = 0.45f * (dup + 0.1f + sqrtf(fmaf(um, um, 1e-4f)));
    }
    gup = fminf(gup, 36.0f);
    return exp2f((gdn + gup) * dp * 0.1660964047443681f);
}

// ---- Pass 0: per-quad composite coefficients; thread id == K linear addr ----
__global__ __launch_bounds__(256) void coef_kernel(const float* __restrict__ x,
                                                   float* __restrict__ K) {
    int l = blockIdx.x * 256 + threadIdx.x;
    int slot = l & 3, b = (l >> 2) & 15, gq = l >> 6;
    int t = gq * 4 + slot;
    if (t >= N_Q) return;
    float4 xq = ((const float4*)x)[b * N_Q + t];
    float v0 = rect_db_f(xq.x), v1 = rect_db_f(xq.y);
    float v2 = rect_db_f(xq.z), v3 = rect_db_f(xq.w);
    float p0 = OMA_AT * v0, q0 = OMA_REL * v0;
    float p1 = OMA_AT * v1, q1 = OMA_REL * v1;
    float p2 = OMA_AT * v2, q2 = OMA_REL * v2;
    float p3 = OMA_AT * v3, q3 = OMA_REL * v3;
    float o1_1 = p0, o1_0 = q0;
    float o2_2 = fmaf(A_AT, o1_1, p1);
    float o2_1 = fmaxf(fmaf(A_AT, o1_0, p1), fmaf(A_REL, o1_1, q1));
    float o2_0 = fmaf(A_REL, o1_0, q1);
    float o3_3 = fmaf(A_AT, o2_2, p2);
    float o3_2 = fmaxf(fmaf(A_AT, o2_1, p2), fmaf(A_REL, o2_2, q2));
    float o3_1 = fmaxf(fmaf(A_AT, o2_0, p2), fmaf(A_REL, o2_1, q2));
    float o3_0 = fmaf(A_REL, o2_0, q2);
    float K4 = fmaf(A_AT, o3_3, p3);
    float K3 = fmaxf(fmaf(A_AT, o3_2, p3), fmaf(A_REL, o3_3, q3));
    float K2 = fmaxf(fmaf(A_AT, o3_1, p3), fmaf(A_REL, o3_2, q3));
    float K1 = fmaxf(fmaf(A_AT, o3_0, p3), fmaf(A_REL, o3_1, q3));
    float K0 = fmaf(A_REL, o3_0, q3);
    K[l]               = K0;
    K[PLANE_F + l]     = K1;
    K[2 * PLANE_F + l] = K2;
    K[3 * PLANE_F + l] = K3;
    K[4 * PLANE_F + l] = K4;
}

// ---- Pass 1: serial scan; 32-quad big-blocks, register double-buffer,
//      sched_barrier(0) fences so the scheduler cannot sink loads to uses ----

#define LOADBB(buf, hb) do {                                              \
    const float4* _p = gp + (size_t)(hb) * 128;                           \
    _Pragma("unroll")                                                     \
    for (int _c = 0; _c < 5; ++_c) {                                      \
        _Pragma("unroll")                                                 \
        for (int _u = 0; _u < 8; ++_u)                                    \
            buf[_c][_u] = *(const vf4*)(_p + (size_t)_c * PSTR4 + _u * 16);\
    }                                                                     \
} while (0)

#define COMPBB(buf, hb) do {                                              \
    const bool _em = ((unsigned)((hb) - e0) < 32u);                       \
    float* _lp = lp + (size_t)(hb) * 32;                                  \
    _Pragma("unroll")                                                     \
    for (int _u = 0; _u < 8; ++_u) {                                      \
        vf4 _o;                                                           \
        _Pragma("unroll")                                                 \
        for (int _e = 0; _e < 4; ++_e) {                                  \
            float c0 = fmaf(S0, s, buf[0][_u][_e]);                       \
            float c1 = fmaf(S1, s, buf[1][_u][_e]);                       \
            float c2 = fmaf(S2, s, buf[2][_u][_e]);                       \
            float c3 = fmaf(S3, s, buf[3][_u][_e]);                       \
            float c4 = fmaf(S4, s, buf[4][_u][_e]);                       \
            s = fmaxf(fmaxf(fmaxf(c0, c1), fmaxf(c2, c3)), c4);           \
            _o[_e] = s;                                                   \
        }                                                                 \
        if (_em) *(vf4*)(_lp + _u * 4) = _o;                              \
    }                                                                     \
} while (0)

#define SFENCE() __builtin_amdgcn_sched_barrier(0)

__global__ __launch_bounds__(64, 1) void scan_kernel(const float* __restrict__ Kf,
                                                     const float* __restrict__ x,
                                                     float* __restrict__ level_q) {
    const int w    = blockIdx.x;            // 0..26
    const int lane = threadIdx.x;
    const int grp  = lane >> 4;
    const int b    = lane & 15;
    const int k    = 4 * w + grp;           // chunk id 0..107
    const int g0   = max(0, (k - 8) * C_Q);
    // big-blocks of 32 quads: (W_Q + C_Q)/32 = 288 for full waves
    const int NHB  = (w >= 2) ? 288 : ((4 * w + 4) * 32);   // wave-uniform, even
    const int e0   = (w >= 2) ? 256 : (k * 32);             // per-lane emit start
    const int nb1  = NHB - 1;

    const float S0 = A_REL * A_REL * A_REL * A_REL;
    const float S1 = A_AT * A_REL * A_REL * A_REL;
    const float S2 = A_AT * A_AT * A_REL * A_REL;
    const float S3 = A_AT * A_AT * A_AT * A_REL;
    const float S4 = A_AT * A_AT * A_AT * A_AT;

    const float4* gp = (const float4*)Kf + (size_t)(g0 >> 2) * 16 + b;
    float* lp = level_q + (size_t)b * KQ_PAD + g0;

    float s = rect_db_f(x[(size_t)b * N_SAMP + 4 * g0]);

    vf4 A[5][8], B[5][8];                   // 320 VGPRs, reg-resident (static idx)
    LOADBB(A, 0);
    SFENCE();

    #pragma clang loop unroll(disable)
    for (int hb = 0; hb < NHB; hb += 2) {
        LOADBB(B, min(hb + 1, nb1));
        SFENCE();                            // loads for B pinned before compute A
        COMPBB(A, hb);
        SFENCE();
        LOADBB(A, min(hb + 2, nb1));
        SFENCE();                            // loads for A pinned before compute B
        COMPBB(B, hb + 1);
        SFENCE();
    }
}

// ---- Pass 2: intra-quad reconstruction + gain + output (parallel) ----
__global__ __launch_bounds__(256) void out_kernel(const float* __restrict__ x,
                                                  const float* __restrict__ level_q,
                                                  const float* __restrict__ thr,
                                                  const float* __restrict__ dep,
                                                  float* __restrict__ out) {
    int t = blockIdx.x * 256 + threadIdx.x;
    int b = blockIdx.y;
    if (t >= N_Q) return;
    float4 xq = ((const float4*)x)[b * N_Q + t];
    float v0 = rect_db_f(xq.x), v1 = rect_db_f(xq.y);
    float v2 = rect_db_f(xq.z), v3 = rect_db_f(xq.w);
    float s = (t == 0) ? v0 : level_q[(size_t)b * KQ_PAD + t - 1];
    float l0 = step_v(s, v0);
    float l1 = step_v(l0, v1);
    float l2 = step_v(l1, v2);
    float l3 = step_v(l2, v3);
    float th = fmaf(thr[b], 40.0f, -40.0f);
    float dp = dep[b];
    float4 o;
    o.x = xq.x * gain_mul(l0, th, dp);
    o.y = xq.y * gain_mul(l1, th, dp);
    o.z = xq.z * gain_mul(l2, th, dp);
    o.w = xq.w * gain_mul(l3, th, dp);
    ((float4*)out)[b * N_Q + t] = o;
}

// ---- Fallback (tiny ws): slow but correct fused scan ----
__global__ __launch_bounds__(64) void scan_fused(const float* __restrict__ x,
                                                 const float* __restrict__ thr,
                                                 const float* __restrict__ dep,
                                                 float* __restrict__ out) {
    int t = blockIdx.x * 64 + threadIdx.x;
    const int NCH = 54, CH = 8192, WM = 32768;
    if (t >= BATCH * NCH) return;
    int b = t / NCH, k = t - b * NCH;
    int start = k * CH, end = min(start + CH, N_SAMP), w0 = max(start - WM, 0);
    const float* xr = x + (size_t)b * N_SAMP;
    float th = fmaf(thr[b], 40.0f, -40.0f);
    float dp = dep[b];
    float s = rect_db_f(xr[w0]);
    for (int j = w0; j < start; ++j) s = step_v(s, rect_db_f(xr[j]));
    float* orow = out + (size_t)b * N_SAMP;
    for (int j = start; j < end; ++j) {
        float xv = xr[j];
        s = step_v(s, rect_db_f(xv));
        orow[j] = xv * gain_mul(s, th, dp);
    }
}

extern "C" void kernel_launch(void* const* d_in, const int* in_sizes, int n_in,
                              void* d_out, int out_size, void* d_ws, size_t ws_size,
                              hipStream_t stream) {
    const float* x   = (const float*)d_in[0];
    const float* thr = (const float*)d_in[1];
    const float* dep = (const float*)d_in[2];
    float* out = (float*)d_out;

    const size_t k_bytes  = (size_t)5 * PLANE_F * sizeof(float);    // 35.4 MB
    const size_t lq_bytes = (size_t)BATCH * KQ_PAD * sizeof(float); // 7.08 MB

    if (ws_size >= k_bytes + lq_bytes) {
        float* K       = (float*)d_ws;
        float* level_q = (float*)((char*)d_ws + k_bytes);
        const int nthread = ((N_Q + 3) / 4) * 64;
        coef_kernel<<<(nthread + 255) / 256, 256, 0, stream>>>(x, K);
        scan_kernel<<<NWAVE, 64, 0, stream>>>(K, x, level_q);
        dim3 gpar((N_Q + 255) / 256, BATCH);
        out_kernel<<<gpar, 256, 0, stream>>>(x, level_q, thr, dep, out);
    } else {
        scan_fused<<<(BATCH * 54 + 63) / 64, 64, 0, stream>>>(x, thr, dep, out);
    }
}